// Round 7
// baseline (249.495 us; speedup 1.0000x reference)
//
#include <hip/hip_runtime.h>

// YOLOv1 loss, faithful to the reference (including the in-place corner bug).
// R7 (discriminator): NO LDS, NO barriers, NO vmcnt(0) drains, NO dynamic
// gather. Each thread owns a 2-cell pair = 240 B = 15 aligned float4 per
// array; all 30 float4 issued back-to-back, compute consumes them under
// fine-grained compiler vmcnt. p[kcol] is selected by cndmask fused into the
// class argmax scan (register-only). One float4 partial per block + reduce.

constexpr int   TPB   = 256;
constexpr int   NC    = 16384 * 7 * 7;   // 802816 cells
constexpr int   NPAIR = NC / 2;          // 401408 row-pairs (240 B each)
constexpr int   NBLK  = NPAIR / TPB;     // 1568 blocks, exact
constexpr float CELL  = 1.0f / 7.0f;
constexpr float LC    = 5.0f;
constexpr float LN    = 0.5f;

__device__ __forceinline__ void cell_terms(const float* __restrict__ pv,
                                           const float* __restrict__ tv,
                                           float& a_cls, float& a_conf,
                                           float& a_cw, float& a_noobj)
{
    const float t4 = tv[4];
    const float obj   = (t4 == 1.0f) ? 1.0f : 0.0f;
    const float noobj = (t4 == 0.0f) ? 1.0f : 0.0f;

    float d4 = pv[4] - t4;
    float d9 = pv[9] - tv[9];
    a_noobj += noobj * (d4 * d4 + d9 * d9);

    // target corners (faithful bug: x2 uses already-updated x1)
    float tw2 = tv[2] * tv[2], th2 = tv[3] * tv[3];
    float tx1 = tv[0] * CELL - 0.5f * tw2;
    float tx2 = tx1 * CELL + 0.5f * tw2;
    float ty1 = tv[1] * CELL - 0.5f * th2;
    float ty2 = ty1 * CELL + 0.5f * th2;
    float area_t = (tx2 - tx1) * (ty2 - ty1);

    float iou0, iou1;
    #pragma unroll
    for (int b = 0; b < 2; ++b) {
        float bw2 = pv[5 * b + 2] * pv[5 * b + 2];
        float bh2 = pv[5 * b + 3] * pv[5 * b + 3];
        float px1 = pv[5 * b + 0] * CELL - 0.5f * bw2;
        float px2 = px1 * CELL + 0.5f * bw2;
        float py1 = pv[5 * b + 1] * CELL - 0.5f * bh2;
        float py2 = py1 * CELL + 0.5f * bh2;
        float ltx = fmaxf(px1, tx1), lty = fmaxf(py1, ty1);
        float rbx = fminf(px2, tx2), rby = fminf(py2, ty2);
        float inter = fmaxf(rbx - ltx, 0.0f) * fmaxf(rby - lty, 0.0f);
        float area_p = (px2 - px1) * (py2 - py1);
        float iou = inter / (area_p + area_t - inter);
        if (b == 0) iou0 = iou; else iou1 = iou;
    }
    const bool b1 = (iou1 > iou0);       // jnp.argmax: first on ties

    float cpx = b1 ? pv[5] : pv[0], ctx = b1 ? tv[5] : tv[0];
    float cpy = b1 ? pv[6] : pv[1], cty = b1 ? tv[6] : tv[1];
    float cpw = b1 ? pv[7] : pv[2], ctw = b1 ? tv[7] : tv[2];
    float cph = b1 ? pv[8] : pv[3], cth = b1 ? tv[8] : tv[3];
    float cpc = b1 ? pv[9] : pv[4], ctc = b1 ? tv[9] : tv[4];

    float dx = cpx - ctx, dy = cpy - cty;
    float dw = cpw - ctw, dh = cph - cth;
    a_cw   += obj * (dx * dx + dy * dy + dw * dw + dh * dh);
    float dc = cpc - ctc;
    a_conf += obj * dc * dc;

    // fused class argmax + p[kcol] select: first occurrence (strict >),
    // pk tracks pv at the winning index -> no memory gather at all
    float best = tv[10];
    float pk   = pv[10];
    #pragma unroll
    for (int k = 11; k < 30; ++k) {
        bool gt = (tv[k] > best);
        best = gt ? tv[k] : best;
        pk   = gt ? pv[k] : pk;
    }
    float dk = pk - best;
    a_cls += obj * dk * dk;
}

__launch_bounds__(TPB, 2)
__global__ void yolo_partial(const float* __restrict__ P, const float* __restrict__ T,
                             float4* __restrict__ ws)
{
    __shared__ float red[4][TPB / 64];

    const int tid  = threadIdx.x;
    const int pair = blockIdx.x * TPB + tid;   // exact, no tail

    // 240-B row-pair, 16-B aligned (240 = 15*16)
    const float4* p4 = reinterpret_cast<const float4*>(P + (size_t)pair * 60);
    const float4* t4 = reinterpret_cast<const float4*>(T + (size_t)pair * 60);

    // issue all 30 loads back-to-back; no drain, compiler uses partial vmcnt
    float4 pr[15], tr[15];
    #pragma unroll
    for (int j = 0; j < 15; ++j) pr[j] = p4[j];
    #pragma unroll
    for (int j = 0; j < 15; ++j) tr[j] = t4[j];

    float pv[60], tv[60];
    #pragma unroll
    for (int j = 0; j < 15; ++j) {
        pv[4 * j + 0] = pr[j].x; pv[4 * j + 1] = pr[j].y;
        pv[4 * j + 2] = pr[j].z; pv[4 * j + 3] = pr[j].w;
        tv[4 * j + 0] = tr[j].x; tv[4 * j + 1] = tr[j].y;
        tv[4 * j + 2] = tr[j].z; tv[4 * j + 3] = tr[j].w;
    }

    float a_cls = 0.f, a_conf = 0.f, a_cw = 0.f, a_noobj = 0.f;
    cell_terms(pv,      tv,      a_cls, a_conf, a_cw, a_noobj);
    cell_terms(pv + 30, tv + 30, a_cls, a_conf, a_cw, a_noobj);

    // block reduction: wave shuffle -> LDS -> one float4 store per block
    float vals[4] = { a_cls, a_conf, a_cw, a_noobj };
    #pragma unroll
    for (int c = 0; c < 4; ++c) {
        #pragma unroll
        for (int off = 32; off > 0; off >>= 1)
            vals[c] += __shfl_down(vals[c], off, 64);
        if ((tid & 63) == 0) red[c][tid >> 6] = vals[c];
    }
    __syncthreads();
    if (tid == 0) {
        float4 s;
        s.x = red[0][0] + red[0][1] + red[0][2] + red[0][3];
        s.y = red[1][0] + red[1][1] + red[1][2] + red[1][3];
        s.z = red[2][0] + red[2][1] + red[2][2] + red[2][3];
        s.w = red[3][0] + red[3][1] + red[3][2] + red[3][3];
        ws[blockIdx.x] = s;              // unique cache line per block
    }
}

__launch_bounds__(1024, 1)
__global__ void yolo_reduce(const float4* __restrict__ ws, float* __restrict__ out)
{
    __shared__ float red[4][16];
    const int tid = threadIdx.x;

    float s0 = 0.f, s1 = 0.f, s2 = 0.f, s3 = 0.f;
    for (int b = tid; b < NBLK; b += 1024) {    // coalesced float4 stream
        float4 v = ws[b];
        s0 += v.x; s1 += v.y; s2 += v.z; s3 += v.w;
    }
    float vals[4] = { s0, s1, s2, s3 };
    #pragma unroll
    for (int c = 0; c < 4; ++c) {
        #pragma unroll
        for (int off = 32; off > 0; off >>= 1)
            vals[c] += __shfl_down(vals[c], off, 64);
        if ((tid & 63) == 0) red[c][tid >> 6] = vals[c];
    }
    __syncthreads();
    if (tid == 0) {
        float t0 = 0.f, t1 = 0.f, t2 = 0.f, t3 = 0.f;
        #pragma unroll
        for (int w = 0; w < 16; ++w) {
            t0 += red[0][w]; t1 += red[1][w]; t2 += red[2][w]; t3 += red[3][w];
        }
        out[0] = LC * t0;                              // cls_loss
        out[1] = LC * t1;                              // conf_loss
        out[2] = LC * t2;                              // center+wh
        out[3] = LN * t3 + LC * (t0 + t1 + t2);        // total
    }
}

extern "C" void kernel_launch(void* const* d_in, const int* in_sizes, int n_in,
                              void* d_out, int out_size, void* d_ws, size_t ws_size,
                              hipStream_t stream) {
    const float* P = (const float*)d_in[0];
    const float* T = (const float*)d_in[1];
    float* out = (float*)d_out;
    float4* ws = (float4*)d_ws;          // NBLK * 16 B = 25088 B of scratch

    yolo_partial<<<NBLK, TPB, 0, stream>>>(P, T, ws);
    yolo_reduce<<<1, 1024, 0, stream>>>(ws, out);
}

// Round 8
// 208.367 us; speedup vs baseline: 1.1974x; 1.1974x over previous
//
#include <hip/hip_runtime.h>

// YOLOv1 loss, faithful to the reference (including the in-place corner bug).
// R8: spill-free max-MLP register streamer. One cell per thread; 15+15 float2
// loads per thread off one base pointer (imm offsets), no LDS data path, no
// barriers, no vmcnt(0) drains; p[kcol] fused into the argmax via cndmask.
// __launch_bounds__(256,4): 128-VGPR cap -> 16 waves/CU resident.
// Session finding: every structure so far delivers bytes/time ~= 2.55 TB/s;
// this is the last untried shape. ~75 us here confirms the service ceiling.

constexpr int   TPB  = 256;
constexpr int   NC   = 16384 * 7 * 7;   // 802816 cells
constexpr int   NBLK = NC / TPB;        // 3136 blocks, exact
constexpr float CELL = 1.0f / 7.0f;
constexpr float LC   = 5.0f;
constexpr float LN   = 0.5f;

// constexpr-folding component access (indices are literals after unroll)
#define PVE(i) (((i) & 1) ? pr[(i) >> 1].y : pr[(i) >> 1].x)
#define TVE(i) (((i) & 1) ? tr[(i) >> 1].y : tr[(i) >> 1].x)

__launch_bounds__(TPB, 4)               // 128 VGPR cap, 16 waves/CU
__global__ void yolo_partial(const float* __restrict__ P, const float* __restrict__ T,
                             float4* __restrict__ ws)
{
    __shared__ float red[4][TPB / 64];

    const int tid  = threadIdx.x;
    const int cell = blockIdx.x * TPB + tid;      // exact, no tail

    const float2* prow = reinterpret_cast<const float2*>(P + (size_t)cell * 30);
    const float2* trow = reinterpret_cast<const float2*>(T + (size_t)cell * 30);

    // 30 independent 8-B loads, all in flight together; single base + imm offs
    float2 pr[15], tr[15];
    #pragma unroll
    for (int j = 0; j < 15; ++j) pr[j] = prow[j];
    #pragma unroll
    for (int j = 0; j < 15; ++j) tr[j] = trow[j];

    const float t4 = TVE(4);
    const float obj   = (t4 == 1.0f) ? 1.0f : 0.0f;
    const float noobj = (t4 == 0.0f) ? 1.0f : 0.0f;

    float d4 = PVE(4) - t4;
    float d9 = PVE(9) - TVE(9);
    float a_noobj = noobj * (d4 * d4 + d9 * d9);

    // target corners (faithful bug: x2 uses already-updated x1)
    float tw2 = TVE(2) * TVE(2), th2 = TVE(3) * TVE(3);
    float tx1 = TVE(0) * CELL - 0.5f * tw2;
    float tx2 = tx1 * CELL + 0.5f * tw2;
    float ty1 = TVE(1) * CELL - 0.5f * th2;
    float ty2 = ty1 * CELL + 0.5f * th2;
    float area_t = (tx2 - tx1) * (ty2 - ty1);

    float iou0, iou1;
    #pragma unroll
    for (int b = 0; b < 2; ++b) {
        float bw2 = PVE(5 * b + 2) * PVE(5 * b + 2);
        float bh2 = PVE(5 * b + 3) * PVE(5 * b + 3);
        float px1 = PVE(5 * b + 0) * CELL - 0.5f * bw2;
        float px2 = px1 * CELL + 0.5f * bw2;
        float py1 = PVE(5 * b + 1) * CELL - 0.5f * bh2;
        float py2 = py1 * CELL + 0.5f * bh2;
        float ltx = fmaxf(px1, tx1), lty = fmaxf(py1, ty1);
        float rbx = fminf(px2, tx2), rby = fminf(py2, ty2);
        float inter = fmaxf(rbx - ltx, 0.0f) * fmaxf(rby - lty, 0.0f);
        float area_p = (px2 - px1) * (py2 - py1);
        float iou = inter / (area_p + area_t - inter);
        if (b == 0) iou0 = iou; else iou1 = iou;
    }
    const bool b1 = (iou1 > iou0);       // jnp.argmax: first on ties

    float cpx = b1 ? PVE(5) : PVE(0), ctx = b1 ? TVE(5) : TVE(0);
    float cpy = b1 ? PVE(6) : PVE(1), cty = b1 ? TVE(6) : TVE(1);
    float cpw = b1 ? PVE(7) : PVE(2), ctw = b1 ? TVE(7) : TVE(2);
    float cph = b1 ? PVE(8) : PVE(3), cth = b1 ? TVE(8) : TVE(3);
    float cpc = b1 ? PVE(9) : PVE(4), ctc = b1 ? TVE(9) : TVE(4);

    float dx = cpx - ctx, dy = cpy - cty;
    float dw = cpw - ctw, dh = cph - cth;
    float a_cw   = obj * (dx * dx + dy * dy + dw * dw + dh * dh);
    float dc = cpc - ctc;
    float a_conf = obj * dc * dc;

    // fused class argmax + p[kcol] select (first occurrence, strict >)
    float best = TVE(10);
    float pk   = PVE(10);
    #pragma unroll
    for (int k = 11; k < 30; ++k) {
        bool gt = (TVE(k) > best);
        best = gt ? TVE(k) : best;
        pk   = gt ? PVE(k) : pk;
    }
    float dk = pk - best;
    float a_cls = obj * dk * dk;

    // ---- block reduction: wave shuffle -> LDS -> one float4 store ----
    float vals[4] = { a_cls, a_conf, a_cw, a_noobj };
    #pragma unroll
    for (int c = 0; c < 4; ++c) {
        #pragma unroll
        for (int off = 32; off > 0; off >>= 1)
            vals[c] += __shfl_down(vals[c], off, 64);
        if ((tid & 63) == 0) red[c][tid >> 6] = vals[c];
    }
    __syncthreads();
    if (tid == 0) {
        float4 s;
        s.x = red[0][0] + red[0][1] + red[0][2] + red[0][3];
        s.y = red[1][0] + red[1][1] + red[1][2] + red[1][3];
        s.z = red[2][0] + red[2][1] + red[2][2] + red[2][3];
        s.w = red[3][0] + red[3][1] + red[3][2] + red[3][3];
        ws[blockIdx.x] = s;              // unique cache line per block
    }
}

__launch_bounds__(1024, 1)
__global__ void yolo_reduce(const float4* __restrict__ ws, float* __restrict__ out)
{
    __shared__ float red[4][16];
    const int tid = threadIdx.x;

    float s0 = 0.f, s1 = 0.f, s2 = 0.f, s3 = 0.f;
    for (int b = tid; b < NBLK; b += 1024) {    // coalesced float4 stream
        float4 v = ws[b];
        s0 += v.x; s1 += v.y; s2 += v.z; s3 += v.w;
    }
    float vals[4] = { s0, s1, s2, s3 };
    #pragma unroll
    for (int c = 0; c < 4; ++c) {
        #pragma unroll
        for (int off = 32; off > 0; off >>= 1)
            vals[c] += __shfl_down(vals[c], off, 64);
        if ((tid & 63) == 0) red[c][tid >> 6] = vals[c];
    }
    __syncthreads();
    if (tid == 0) {
        float t0 = 0.f, t1 = 0.f, t2 = 0.f, t3 = 0.f;
        #pragma unroll
        for (int w = 0; w < 16; ++w) {
            t0 += red[0][w]; t1 += red[1][w]; t2 += red[2][w]; t3 += red[3][w];
        }
        out[0] = LC * t0;                              // cls_loss
        out[1] = LC * t1;                              // conf_loss
        out[2] = LC * t2;                              // center+wh
        out[3] = LN * t3 + LC * (t0 + t1 + t2);        // total
    }
}

extern "C" void kernel_launch(void* const* d_in, const int* in_sizes, int n_in,
                              void* d_out, int out_size, void* d_ws, size_t ws_size,
                              hipStream_t stream) {
    const float* P = (const float*)d_in[0];
    const float* T = (const float*)d_in[1];
    float* out = (float*)d_out;
    float4* ws = (float4*)d_ws;          // NBLK * 16 B = 50176 B of scratch

    yolo_partial<<<NBLK, TPB, 0, stream>>>(P, T, ws);
    yolo_reduce<<<1, 1024, 0, stream>>>(ws, out);
}